// Round 2
// baseline (14315.886 us; speedup 1.0000x reference)
//
#include <hip/hip_runtime.h>
#include <stdint.h>

#define T_STEPS 512
#define NB 64
#define HID 1024
#define G4 4096

typedef __attribute__((ext_vector_type(8))) short bf16x8;
typedef __attribute__((ext_vector_type(4))) float f32x4;

__device__ inline unsigned short f2bf(float f) {
  unsigned int u = __float_as_uint(f);
  return (unsigned short)((u + 0x7fffu + ((u >> 16) & 1u)) >> 16);
}
__device__ inline unsigned int pack2bf(float lo, float hi) {
  return (unsigned int)f2bf(lo) | ((unsigned int)f2bf(hi) << 16);
}

// ---------------- fp32 -> bf16 conversion (for W_hh) ----------------
__global__ __launch_bounds__(256) void cvt_bf16_kernel(const float4* __restrict__ src,
                                                       ushort4* __restrict__ dst) {
  int i = blockIdx.x * 256 + threadIdx.x;
  float4 v = src[i];
  ushort4 r;
  r.x = f2bf(v.x); r.y = f2bf(v.y); r.z = f2bf(v.z); r.w = f2bf(v.w);
  dst[i] = r;
}

// ---------------- zero-init c-state and h double buffer ----------------
__global__ __launch_bounds__(256) void init_state_kernel(float* __restrict__ c_state,
                                                         unsigned short* __restrict__ h_buf) {
  int i = blockIdx.x * 256 + threadIdx.x;   // 0..131071
  if (i < NB * HID) c_state[i] = 0.0f;
  h_buf[i] = 0;                              // covers both h buffers (2*64*1024)
}

// ---------------- phase 1 (chunked): xp_c = x[:, t0:t0+TC] @ W_ih^T + bias ----------------
// A rows (chunk-local r = b*TC + dt) map to x row b*512 + t0 + dt. fp32 loaded,
// converted to bf16 during LDS staging. C chunk fp32 [64*TC][4096].
#define BM 128
#define BN 128
#define BK 32
#define LDT 72   // LDS row stride (bf16 elems); 144B rows keep 16B alignment

__global__ __launch_bounds__(256, 2) void gemm_xproj_chunk(
    const float* __restrict__ x,      // [64*512][1024] fp32
    const float* __restrict__ Wih,    // [4096][1024] fp32
    const float* __restrict__ b_ih,
    const float* __restrict__ b_hh,
    float* __restrict__ Cc,           // [64*TC][4096] fp32
    int t0, int tclog2) {
  __shared__ unsigned short As[BM * LDT];
  __shared__ unsigned short Bs[BN * LDT];
  const int tid = threadIdx.x;
  const int m0 = blockIdx.x * BM;
  const int n0 = blockIdx.y * BN;
  const int wave = tid >> 6, lane = tid & 63;
  const int wm = (wave & 1) * 64, wn = (wave >> 1) * 64;
  const int lq = lane >> 4, lr = lane & 15;
  // staging assignment: thread covers 16 contiguous fp32 of one row of each tile
  const int srow = tid >> 1;
  const int scol = (tid & 1) * 16;
  const int am = m0 + srow;
  const int ab = am >> tclog2, adt = am & ((1 << tclog2) - 1);
  const float* arow = x + (size_t)(ab * 512 + t0 + adt) * 1024 + scol;
  const float* brow = Wih + (size_t)(n0 + srow) * 1024 + scol;
  unsigned short* asd = As + srow * LDT + scol;
  unsigned short* bsd = Bs + srow * LDT + scol;
  f32x4 acc[4][4] = {};
  for (int kk = 0; kk < 1024; kk += BK) {
    float4 a0 = *(const float4*)(arow + kk);
    float4 a1 = *(const float4*)(arow + kk + 4);
    float4 a2 = *(const float4*)(arow + kk + 8);
    float4 a3 = *(const float4*)(arow + kk + 12);
    float4 w0 = *(const float4*)(brow + kk);
    float4 w1 = *(const float4*)(brow + kk + 4);
    float4 w2 = *(const float4*)(brow + kk + 8);
    float4 w3 = *(const float4*)(brow + kk + 12);
    __syncthreads();   // previous iter's fragment reads complete before overwrite
    uint4 pa0, pa1, pb0, pb1;
    pa0.x = pack2bf(a0.x, a0.y); pa0.y = pack2bf(a0.z, a0.w);
    pa0.z = pack2bf(a1.x, a1.y); pa0.w = pack2bf(a1.z, a1.w);
    pa1.x = pack2bf(a2.x, a2.y); pa1.y = pack2bf(a2.z, a2.w);
    pa1.z = pack2bf(a3.x, a3.y); pa1.w = pack2bf(a3.z, a3.w);
    pb0.x = pack2bf(w0.x, w0.y); pb0.y = pack2bf(w0.z, w0.w);
    pb0.z = pack2bf(w1.x, w1.y); pb0.w = pack2bf(w1.z, w1.w);
    pb1.x = pack2bf(w2.x, w2.y); pb1.y = pack2bf(w2.z, w2.w);
    pb1.z = pack2bf(w3.x, w3.y); pb1.w = pack2bf(w3.z, w3.w);
    *(uint4*)(asd) = pa0; *(uint4*)(asd + 8) = pa1;
    *(uint4*)(bsd) = pb0; *(uint4*)(bsd + 8) = pb1;
    __syncthreads();
    bf16x8 af[4], bfr[4];
    #pragma unroll
    for (int i = 0; i < 4; ++i) {
      af[i]  = *(const bf16x8*)(As + (wm + i * 16 + lr) * LDT + lq * 8);
      bfr[i] = *(const bf16x8*)(Bs + (wn + i * 16 + lr) * LDT + lq * 8);
    }
    #pragma unroll
    for (int mt = 0; mt < 4; ++mt)
      #pragma unroll
      for (int nt = 0; nt < 4; ++nt)
        acc[mt][nt] = __builtin_amdgcn_mfma_f32_16x16x32_bf16(af[mt], bfr[nt], acc[mt][nt], 0, 0, 0);
  }
  // epilogue: D[m=(lane>>4)*4+r][n=lane&15]
  #pragma unroll
  for (int nt = 0; nt < 4; ++nt) {
    int col = n0 + wn + nt * 16 + lr;
    float bias = b_ih[col] + b_hh[col];
    #pragma unroll
    for (int mt = 0; mt < 4; ++mt) {
      int rb = m0 + wm + mt * 16 + lq * 4;
      #pragma unroll
      for (int r = 0; r < 4; ++r)
        Cc[(size_t)(rb + r) * G4 + col] = acc[mt][nt][r] + bias;
    }
  }
}

// ---------------- phase 2: one LSTM step ----------------
// 64 blocks x 256 thr. Block u owns hidden units [16u,16u+16); wave w = gate
// (0=f,1=i,2=o,3=g). W_hh frags register-resident; h read direct from global (L2-hot).
__global__ __launch_bounds__(256, 1) void lstm_step_kernel(
    const unsigned short* __restrict__ Whh,   // bf16 [4096][1024]
    const float* __restrict__ xc,             // chunk [64*TC][4096] fp32
    const unsigned short* __restrict__ h_in,  // bf16 [64][1024]
    unsigned short* __restrict__ h_out,       // bf16 [64][1024]
    float* __restrict__ c_state,              // fp32 [64][1024]
    float* __restrict__ out,                  // fp32 [64*512][1024]
    int t, int dt, int tclog2) {
  __shared__ float gb[4][NB][16];             // activated gates (16KB)
  const int tid = threadIdx.x;
  const int u = blockIdx.x;
  const int wave = tid >> 6, lane = tid & 63;
  const int lq = lane >> 4, lr = lane & 15;
  const int rowbase = wave * HID + u * 16;
  const unsigned short* wrow = Whh + (size_t)(rowbase + lr) * HID + lq * 8;
  bf16x8 wf[32];
  #pragma unroll
  for (int kk = 0; kk < 32; ++kk) wf[kk] = *(const bf16x8*)(wrow + kk * 32);
  f32x4 accA[4] = {}, accB[4] = {};
  #pragma unroll
  for (int mt = 0; mt < 4; ++mt) {
    const unsigned short* hp = h_in + (size_t)(mt * 16 + lr) * HID + lq * 8;
    #pragma unroll
    for (int kk = 0; kk < 32; kk += 2) {
      bf16x8 a0 = *(const bf16x8*)(hp + kk * 32);
      bf16x8 a1 = *(const bf16x8*)(hp + kk * 32 + 32);
      accA[mt] = __builtin_amdgcn_mfma_f32_16x16x32_bf16(a0, wf[kk], accA[mt], 0, 0, 0);
      accB[mt] = __builtin_amdgcn_mfma_f32_16x16x32_bf16(a1, wf[kk + 1], accB[mt], 0, 0, 0);
    }
  }
  #pragma unroll
  for (int mt = 0; mt < 4; ++mt) {
    f32x4 a = accA[mt] + accB[mt];
    #pragma unroll
    for (int r = 0; r < 4; ++r) {
      int b = mt * 16 + lq * 4 + r;
      float pre = a[r] + xc[(size_t)((b << tclog2) + dt) * G4 + rowbase + lr];
      float v;
      if (wave == 3) v = 2.0f / (1.0f + __expf(-2.0f * pre)) - 1.0f;  // tanh
      else           v = 1.0f / (1.0f + __expf(-pre));                 // sigmoid
      gb[wave][b][lr] = v;
    }
  }
  __syncthreads();
  #pragma unroll
  for (int j = 0; j < 4; ++j) {
    int idx = tid + j * 256;
    int b = idx >> 4, n = idx & 15;
    float f = gb[0][b][n], i = gb[1][b][n], o = gb[2][b][n], g = gb[3][b][n];
    int ci = b * HID + u * 16 + n;
    float c = f * c_state[ci] + i * g;
    c_state[ci] = c;
    float th = 2.0f / (1.0f + __expf(-2.0f * c)) - 1.0f;
    float h = o * th;
    out[(size_t)(b * T_STEPS + t) * HID + u * 16 + n] = h;
    h_out[ci] = f2bf(h);
  }
}

extern "C" void kernel_launch(void* const* d_in, const int* in_sizes, int n_in,
                              void* d_out, int out_size, void* d_ws, size_t ws_size,
                              hipStream_t stream) {
  const float* x    = (const float*)d_in[0];
  const float* W_ih = (const float*)d_in[1];
  const float* W_hh = (const float*)d_in[2];
  const float* b_ih = (const float*)d_in[3];
  const float* b_hh = (const float*)d_in[4];
  float* out = (float*)d_out;
  char* ws = (char*)d_ws;

  // fixed allocations: bf16 W_hh (8MB) + c_state (256KB) + h double buffer (256KB)
  const size_t whh_bytes = (size_t)G4 * HID * 2;
  const size_t c_bytes   = (size_t)NB * HID * 4;
  const size_t h_bytes   = (size_t)2 * NB * HID * 2;
  const size_t fixed = whh_bytes + c_bytes + h_bytes;
  // adaptive time-chunk: largest TC in {64..2} whose fp32 chunk buffer fits
  int tclog2 = 6;
  while (tclog2 > 1) {
    size_t need = fixed + (((size_t)NB << tclog2) * G4 * 4);
    if (need <= ws_size) break;
    --tclog2;
  }
  const int TC = 1 << tclog2;

  size_t off = 0;
  float* chunk = (float*)(ws + off);                  off += ((size_t)NB << tclog2) * G4 * 4;
  unsigned short* whhb = (unsigned short*)(ws + off); off += whh_bytes;
  float* c_state = (float*)(ws + off);                off += c_bytes;
  unsigned short* h_buf = (unsigned short*)(ws + off);

  init_state_kernel<<<512, 256, 0, stream>>>(c_state, h_buf);
  cvt_bf16_kernel<<<4096, 256, 0, stream>>>((const float4*)W_hh, (ushort4*)whhb);

  const int n_chunks = T_STEPS >> tclog2;
  for (int c = 0; c < n_chunks; ++c) {
    const int t0 = c << tclog2;
    gemm_xproj_chunk<<<dim3(TC / 2, 32), 256, 0, stream>>>(x, W_ih, b_ih, b_hh,
                                                           chunk, t0, tclog2);
    for (int dt = 0; dt < TC; ++dt) {
      const int t = t0 + dt;
      const unsigned short* hi = h_buf + (size_t)(t & 1) * (NB * HID);
      unsigned short* ho = h_buf + (size_t)((t + 1) & 1) * (NB * HID);
      lstm_step_kernel<<<64, 256, 0, stream>>>(whhb, chunk, hi, ho, c_state, out,
                                               t, dt, tclog2);
    }
  }
}